// Round 8
// baseline (815.895 us; speedup 1.0000x reference)
//
#include <hip/hip_runtime.h>
#include <math.h>

#define D_MODEL 1024
#define NH 16
#define DK 64
#define BB 2
#define SS 2048
#define BH (BB * NH)      // 32
#define M_TOT (BB * SS)   // 4096
#define QBLK 128
#define NSTRIP (SS / QBLK)  // 16

typedef __bf16 bf16x8 __attribute__((ext_vector_type(8)));
typedef float f32x4 __attribute__((ext_vector_type(4)));

static __device__ __forceinline__ unsigned short f2bf(float x) {
  unsigned int u = __float_as_uint(x);
  u = (u + 0x7fffu + ((u >> 16) & 1u)) >> 16;  // RNE
  return (unsigned short)u;
}

static __device__ __forceinline__ bf16x8 cvt8(float4 a, float4 b) {
  bf16x8 v;
  v[0] = (__bf16)a.x; v[1] = (__bf16)a.y; v[2] = (__bf16)a.z; v[3] = (__bf16)a.w;
  v[4] = (__bf16)b.x; v[5] = (__bf16)b.y; v[6] = (__bf16)b.z; v[7] = (__bf16)b.w;
  return v;
}

// ---------------------------------------------------------------------------
// GEMM body: y[m,n] = sum_k X[m,k]*W[n,k] + bias[n]
// Tile 128(m) x 128(n), BK=64, 256 threads = 4 waves; wave owns 32 rows x 128.
// IN_F32: X is fp32 (converted in staging); else X is bf16.
// W is always fp32 (converted in staging).
// MODE 0: write bf16 head-split [b,h,s,dk]   MODE 1: write fp32 [m,n]
// ---------------------------------------------------------------------------
template <int IN_F32, int MODE>
static __device__ __forceinline__ void proj_body(
    const void* __restrict__ Xv, const float* __restrict__ W,
    const float* __restrict__ bias, void* __restrict__ Yv, int m0, int n0) {
  __shared__ __align__(16) unsigned short As[128][72];
  __shared__ __align__(16) unsigned short Bs[128][72];
  const int tid = threadIdx.x;
  const int wave = tid >> 6, lane = tid & 63;
  const int lrow = lane & 15, lkc = lane >> 4;

  f32x4 acc[2][8] = {};

  for (int kt = 0; kt < D_MODEL; kt += 64) {
    __syncthreads();
    // stage A: 128 rows x 64 cols (8 bf16-chunks/row), 1024 units, 4/thread
#pragma unroll
    for (int i = 0; i < 4; ++i) {
      const int u = tid + 256 * i, r = u >> 3, c8 = (u & 7) * 8;
      if (IN_F32) {
        const float4* xp = reinterpret_cast<const float4*>(
            (const float*)Xv + (size_t)(m0 + r) * D_MODEL + kt + c8);
        *reinterpret_cast<bf16x8*>(&As[r][c8]) = cvt8(xp[0], xp[1]);
      } else {
        *reinterpret_cast<uint4*>(&As[r][c8]) = *reinterpret_cast<const uint4*>(
            (const unsigned short*)Xv + (size_t)(m0 + r) * D_MODEL + kt + c8);
      }
    }
    // stage B: 128 rows (n) x 64 cols, fp32 -> bf16
#pragma unroll
    for (int i = 0; i < 4; ++i) {
      const int u = tid + 256 * i, r = u >> 3, c8 = (u & 7) * 8;
      const float4* wp = reinterpret_cast<const float4*>(
          W + (size_t)(n0 + r) * D_MODEL + kt + c8);
      *reinterpret_cast<bf16x8*>(&Bs[r][c8]) = cvt8(wp[0], wp[1]);
    }
    __syncthreads();
#pragma unroll
    for (int kk = 0; kk < 64; kk += 32) {
      bf16x8 a0 = *reinterpret_cast<const bf16x8*>(
          &As[wave * 32 + lrow][kk + lkc * 8]);
      bf16x8 a1 = *reinterpret_cast<const bf16x8*>(
          &As[wave * 32 + 16 + lrow][kk + lkc * 8]);
#pragma unroll
      for (int nj = 0; nj < 8; ++nj) {
        bf16x8 b = *reinterpret_cast<const bf16x8*>(
            &Bs[nj * 16 + lrow][kk + lkc * 8]);
        acc[0][nj] = __builtin_amdgcn_mfma_f32_16x16x32_bf16(a0, b, acc[0][nj], 0, 0, 0);
        acc[1][nj] = __builtin_amdgcn_mfma_f32_16x16x32_bf16(a1, b, acc[1][nj], 0, 0, 0);
      }
    }
  }

#pragma unroll
  for (int mi = 0; mi < 2; ++mi) {
#pragma unroll
    for (int nj = 0; nj < 8; ++nj) {
      const int nfull = n0 + nj * 16 + lrow;
      const float bv = bias[nfull];
#pragma unroll
      for (int j = 0; j < 4; ++j) {
        const int m = m0 + wave * 32 + mi * 16 + lkc * 4 + j;
        const float val = acc[mi][nj][j] + bv;
        if (MODE == 0) {
          const int b = m >> 11, s = m & 2047;
          const int h = nfull >> 6, d = nfull & 63;
          reinterpret_cast<unsigned short*>(Yv)
              [((size_t)(b * NH + h) * SS + s) * DK + d] = f2bf(val);
        } else {
          reinterpret_cast<float*>(Yv)[(size_t)m * D_MODEL + nfull] = val;
        }
      }
    }
  }
}

// Fused Q/K/V projections (fp32 inputs + fp32 weights, fused cvt).
__global__ __launch_bounds__(256) void proj_qkv_82592221102086(
    const float* __restrict__ Q, const float* __restrict__ K,
    const float* __restrict__ V, const float* __restrict__ Wq,
    const float* __restrict__ Wk, const float* __restrict__ Wv,
    const float* __restrict__ bq, const float* __restrict__ bk,
    const float* __restrict__ bv, unsigned short* __restrict__ qbv,
    unsigned short* __restrict__ kbv, unsigned short* __restrict__ vbv) {
  const float *X, *W, *bias;
  unsigned short* Y;
  if (blockIdx.z == 0) { X = Q; W = Wq; bias = bq; Y = qbv; }
  else if (blockIdx.z == 1) { X = K; W = Wk; bias = bk; Y = kbv; }
  else { X = V; W = Wv; bias = bv; Y = vbv; }
  proj_body<1, 0>(X, W, bias, Y, blockIdx.y * 128, blockIdx.x * 128);
}

// Output projection: bf16 ctx input, fp32 Wo, fp32 output.
__global__ __launch_bounds__(256) void proj_out_82592221102086(
    const unsigned short* __restrict__ ctx, const float* __restrict__ Wo,
    const float* __restrict__ bo, float* __restrict__ out) {
  proj_body<0, 1>(ctx, Wo, bo, out, blockIdx.y * 128, blockIdx.x * 128);
}

// ---------------------------------------------------------------------------
// Two-pass MFMA causal attention. One (b,h) x one 128-row q strip per block.
// 512 threads = 8 waves, each wave owns 16 q rows. KV tiles of 64.
// Pass A: QK^T + exp -> row sums. Pass B: recompute, write NORMALIZED p
// directly from registers (nontemporal dwords, 64B runs per 16 lanes),
// PV with bf16 frags via Ps (same-wave LDS round trip, no barrier).
// Per-block attn write is constant 1 MB; qt complement pairing balances work.
// LDS 38 KB -> 4 blocks/CU.
// ---------------------------------------------------------------------------
__global__ __launch_bounds__(512, 4) void attn_mfma_82592221102086(
    const unsigned short* __restrict__ qb, const unsigned short* __restrict__ kb,
    const unsigned short* __restrict__ vb, float* __restrict__ attn,
    unsigned short* __restrict__ ctx) {
  __shared__ __align__(16) unsigned short Ks[64][72];    // [t][d]
  __shared__ __align__(16) unsigned short Vt[64][72];    // [d][t-swizzled]
  __shared__ __align__(16) unsigned short Ps[QBLK][76];  // [qrow][t] bf16

  const int bi = blockIdx.x;                // 0..511
  const int xcd = bi & 7, slot = bi >> 3;   // slot 0..63
  const int bhl = (slot >> 4) & 3;
  const int bh = xcd * 4 + bhl;
  const int u = slot & 15;
  const int qt = (bhl & 2) ? (15 - u) : u;  // complementary qt pairing
  const int qs = qt * QBLK;
  const int ntile = 2 * qt + 2;             // kv tiles with data
  const int tid = threadIdx.x;
  const int wave = tid >> 6, lane = tid & 63;
  const int lrow = lane & 15, lkc = lane >> 4;

  const unsigned short* qrow =
      qb + ((size_t)bh * SS + qs + wave * 16 + lrow) * DK;
  const bf16x8 qf0 = *reinterpret_cast<const bf16x8*>(qrow + lkc * 8);
  const bf16x8 qf1 = *reinterpret_cast<const bf16x8*>(qrow + 32 + lkc * 8);

  float lsum[4] = {};

  // ---------------- Pass A: row sums ----------------
  for (int kt = 0; kt < ntile; ++kt) {
    const int ks = kt * 64;
    __syncthreads();
    {
      const int r = tid >> 3, c8 = (tid & 7) * 8;
      *reinterpret_cast<uint4*>(&Ks[r][c8]) = *reinterpret_cast<const uint4*>(
          &kb[((size_t)bh * SS + ks + r) * DK + c8]);
    }
    __syncthreads();

    f32x4 sacc[4] = {};
#pragma unroll
    for (int kk = 0; kk < 64; kk += 32) {
      const bf16x8 qf = (kk == 0) ? qf0 : qf1;
#pragma unroll
      for (int tj = 0; tj < 4; ++tj) {
        bf16x8 kf = *reinterpret_cast<const bf16x8*>(
            &Ks[tj * 16 + lrow][kk + lkc * 8]);
        sacc[tj] = __builtin_amdgcn_mfma_f32_16x16x32_bf16(qf, kf, sacc[tj], 0, 0, 0);
      }
    }
    const bool diag = (kt >= ntile - 2);
#pragma unroll
    for (int tj = 0; tj < 4; ++tj) {
#pragma unroll
      for (int j = 0; j < 4; ++j) {
        const int grow = qs + wave * 16 + lkc * 4 + j;
        const int gcol = ks + tj * 16 + lrow;
        if (!diag || gcol <= grow)
          lsum[j] += __expf(fminf(sacc[tj][j] * 0.125f, 80.f));
      }
    }
  }

  float inv[4];
#pragma unroll
  for (int j = 0; j < 4; ++j) {
    float l = lsum[j];
#pragma unroll
    for (int m = 1; m < 16; m <<= 1) l += __shfl_xor(l, m, 64);
    inv[j] = 1.0f / l;
  }

  // ---------------- Pass B: normalized p write + PV ----------------
  f32x4 oacc[4] = {};

  for (int kt = 0; kt < ntile; ++kt) {
    const int ks = kt * 64;
    __syncthreads();
    {  // stage K
      const int r = tid >> 3, c8 = (tid & 7) * 8;
      *reinterpret_cast<uint4*>(&Ks[r][c8]) = *reinterpret_cast<const uint4*>(
          &kb[((size_t)bh * SS + ks + r) * DK + c8]);
    }
    {  // stage V transposed+swizzled: V[t][d] -> Vt[d][t ^ 8*((d>>3)&7)]
      const int t = tid >> 3, d0 = (tid & 7) * 8;
      uint4 raw = *reinterpret_cast<const uint4*>(
          &vb[((size_t)bh * SS + ks + t) * DK + d0]);
      const unsigned short* pv = reinterpret_cast<const unsigned short*>(&raw);
      const int tsw = t ^ d0;  // d0 = 8*(d0/8)
#pragma unroll
      for (int jj = 0; jj < 8; ++jj) Vt[d0 + jj][tsw] = pv[jj];
    }
    __syncthreads();

    f32x4 sacc[4] = {};
#pragma unroll
    for (int kk = 0; kk < 64; kk += 32) {
      const bf16x8 qf = (kk == 0) ? qf0 : qf1;
#pragma unroll
      for (int tj = 0; tj < 4; ++tj) {
        bf16x8 kf = *reinterpret_cast<const bf16x8*>(
            &Ks[tj * 16 + lrow][kk + lkc * 8]);
        sacc[tj] = __builtin_amdgcn_mfma_f32_16x16x32_bf16(qf, kf, sacc[tj], 0, 0, 0);
      }
    }

    const bool diag = (kt >= ntile - 2);
#pragma unroll
    for (int tj = 0; tj < 4; ++tj) {
#pragma unroll
      for (int j = 0; j < 4; ++j) {
        const int prow = wave * 16 + lkc * 4 + j;
        const int grow = qs + prow;
        const int gcol = ks + tj * 16 + lrow;
        float pv = 0.f;
        if (!diag || gcol <= grow)
          pv = __expf(fminf(sacc[tj][j] * 0.125f, 80.f)) * inv[j];
        __builtin_nontemporal_store(
            pv, &attn[((size_t)bh * SS + grow) * SS + gcol]);
        *reinterpret_cast<__bf16*>(&Ps[prow][tj * 16 + lrow]) = (__bf16)pv;
      }
    }
    // PV: own-wave Ps rows (same-wave RAW ordered by lgkmcnt), Vt barrier-safe
#pragma unroll
    for (int kk2 = 0; kk2 < 64; kk2 += 32) {
      bf16x8 pf = *reinterpret_cast<const bf16x8*>(
          &Ps[wave * 16 + lrow][kk2 + lkc * 8]);
#pragma unroll
      for (int dj = 0; dj < 4; ++dj) {
        const int d = dj * 16 + lrow;
        const int tch = ((kk2 >> 3) + lkc) ^ (d >> 3);
        bf16x8 vf = *reinterpret_cast<const bf16x8*>(&Vt[d][tch << 3]);
        oacc[dj] = __builtin_amdgcn_mfma_f32_16x16x32_bf16(pf, vf, oacc[dj], 0, 0, 0);
      }
    }
  }

  // ---------------- context write (already normalized) ----------------
  const int b = bh >> 4, h = bh & 15;
#pragma unroll
  for (int dj = 0; dj < 4; ++dj) {
    const int d = dj * 16 + lrow;
#pragma unroll
    for (int j = 0; j < 4; ++j) {
      const int row = qs + wave * 16 + lkc * 4 + j;
      ctx[((size_t)(b * SS + row)) * D_MODEL + h * DK + d] = f2bf(oacc[dj][j]);
    }
  }

  // ---------------- zero-fill remaining tiles ----------------
  const f32x4 z4 = {0.f, 0.f, 0.f, 0.f};
  for (int kt = ntile; kt < 32; ++kt) {
    const int ks = kt * 64;
#pragma unroll
    for (int it = 0; it < 4; ++it) {
      const int r = it * 32 + (tid >> 4), c0 = (tid & 15) * 4;
      __builtin_nontemporal_store(
          z4, reinterpret_cast<f32x4*>(
                  &attn[((size_t)bh * SS + qs + r) * SS + ks + c0]));
    }
  }
}

// ---------------------------------------------------------------------------
extern "C" void kernel_launch(void* const* d_in, const int* in_sizes, int n_in,
                              void* d_out, int out_size, void* d_ws,
                              size_t ws_size, hipStream_t stream) {
  const float* Q = (const float*)d_in[0];
  const float* K = (const float*)d_in[1];
  const float* V = (const float*)d_in[2];
  const float* Wq = (const float*)d_in[4];
  const float* bq = (const float*)d_in[5];
  const float* Wk = (const float*)d_in[6];
  const float* bk = (const float*)d_in[7];
  const float* Wv = (const float*)d_in[8];
  const float* bv = (const float*)d_in[9];
  const float* Wo = (const float*)d_in[10];
  const float* bo = (const float*)d_in[11];

  float* out = (float*)d_out;                   // [B,S,D_MODEL] fp32
  float* attn = out + (size_t)M_TOT * D_MODEL;  // [B,H,S,S] fp32

  const size_t nX = (size_t)M_TOT * D_MODEL;  // 4,194,304
  unsigned short* ws = (unsigned short*)d_ws;
  unsigned short* qbv = ws;
  unsigned short* kbv = qbv + nX;
  unsigned short* vbv = kbv + nX;
  unsigned short* ctx = vbv + nX;

  proj_qkv_82592221102086<<<dim3(D_MODEL / 128, M_TOT / 128, 3), 256, 0,
                            stream>>>(Q, K, V, Wq, Wk, Wv, bq, bk, bv,
                                      qbv, kbv, vbv);

  attn_mfma_82592221102086<<<dim3(BH * NSTRIP), 512, 0, stream>>>(
      qbv, kbv, vbv, attn, ctx);

  proj_out_82592221102086<<<dim3(D_MODEL / 128, M_TOT / 128), 256, 0, stream>>>(
      ctx, Wo, bo, out);
}